// Round 6
// baseline (33.679 us; speedup 1.0000x reference)
//
#include <hip/hip_runtime.h>
#include <math.h>

#define THREADS    64      // one wave per block
#define EPB        8       // elements per block
#define NI         9
#define NT         17
#define DEPTH      8

#define MAG_MAX    1e28f
#define MAG_MIN    1e-12f
#define LOG_LIM    100.0f
#define LOG_MAG_MIN (-27.631021115928547f)   // logf(1e-12)

typedef __attribute__((address_space(1))) const unsigned char gconst_byte;
typedef __attribute__((address_space(3))) unsigned char lds_byte;

__device__ __forceinline__ void gl_lds16(const float* g, float* l) {
    __builtin_amdgcn_global_load_lds((gconst_byte*)(const void*)g,
                                     (lds_byte*)(void*)l, 16, 0, 0);
}
__device__ __forceinline__ void gl_lds4(const float* g, float* l) {
    __builtin_amdgcn_global_load_lds((gconst_byte*)(const void*)g,
                                     (lds_byte*)(void*)l, 4, 0, 0);
}

__device__ __forceinline__ float tanh_fast(float x) {
    float e = __expf(2.0f * x);
    return 1.0f - 2.0f / (e + 1.0f);
}

__global__ __launch_bounds__(THREADS, 4)
void dag_exec_kernel(const float* __restrict__ dl,   // [NE,9,8,10]
                     const float* __restrict__ vsg,  // [NE,17]
                     const float* __restrict__ Og,   // [NE,8,17]
                     const float* __restrict__ Gg,   // [NE,8]
                     float* __restrict__ out)        // [NE]
{
    __shared__ float s_dl[640];         // 2.5 KB digit chunk buffer (single wave)
    __shared__ float s_init[EPB * 9];
    __shared__ float s_O[EPB * 136];    // 1088 dw, global_load_lds destination
    __shared__ float s_vs[EPB * NT];    // 136 dw
    __shared__ float s_G[EPB * 9];

    const int lane = threadIdx.x;
    const long e0  = (long)blockIdx.x * EPB;
    const float* Dg = dl + e0 * 720;    // 5760 dw = 9 chunks of 640

    // ---- depth-2 register pipeline: issue chunks 0 and 1 now ----
    float4 A0[3], A1[3];
    float2 A2[3];
    A0[0] = *(const float4*)(Dg + lane * 4);
    A1[0] = *(const float4*)(Dg + 256 + lane * 4);
    A2[0] = *(const float2*)(Dg + 512 + lane * 2);
    A0[1] = *(const float4*)(Dg + 640 + lane * 4);
    A1[1] = *(const float4*)(Dg + 640 + 256 + lane * 4);
    A2[1] = *(const float2*)(Dg + 640 + 512 + lane * 2);

    // ---- O -> LDS direct (coalesced): 4 x 1KB + 1 x 256B ----
    {
        const float* Ob = Og + e0 * 136;         // 1088 dw
        gl_lds16(Ob + lane * 4,        s_O);
        gl_lds16(Ob + 256 + lane * 4,  s_O + 256);
        gl_lds16(Ob + 512 + lane * 4,  s_O + 512);
        gl_lds16(Ob + 768 + lane * 4,  s_O + 768);
        gl_lds4 (Ob + 1024 + lane,     s_O + 1024);
    }
    // ---- V_sign (136 dw), G (64 dw) ----
    {
        const float* Vb = vsg + e0 * NT;
        s_vs[lane]      = Vb[lane];
        s_vs[lane + 64] = Vb[lane + 64];
        if (lane < 8) s_vs[lane + 128] = Vb[lane + 128];
        s_G[(lane >> 3) * 9 + (lane & 7)] = Gg[e0 * 8 + lane];
    }

    const int dpos = lane & 7;
    const float powv = (dpos == 0) ? 1000.0f : (dpos == 1) ? 100.0f : (dpos == 2) ? 10.0f :
                       (dpos == 3) ? 1.0f    : (dpos == 4) ? 0.1f   : (dpos == 5) ? 0.01f :
                       (dpos == 6) ? 0.001f  : 0.0001f;

    // ---- phase 1: 9 chunks of 64 slots, wave-local, barrier-free ----
    #pragma unroll
    for (int c = 0; c < 9; ++c) {
        const int cur = c % 3;                    // compile-time under unroll
        const int pre = (c + 2) % 3;
        if (c + 2 < 9) {
            const float* gn = Dg + (c + 2) * 640;
            A0[pre] = *(const float4*)(gn + lane * 4);
            A1[pre] = *(const float4*)(gn + 256 + lane * 4);
            A2[pre] = *(const float2*)(gn + 512 + lane * 2);
        }

        *(float4*)(s_dl + lane * 4)       = A0[cur];
        *(float4*)(s_dl + 256 + lane * 4) = A1[cur];
        *(float2*)(s_dl + 512 + lane * 2) = A2[cur];

        const float* p = s_dl + lane * 10;        // own record
        float2 a0 = *(const float2*)(p + 0);
        float2 a1 = *(const float2*)(p + 2);
        float2 a2 = *(const float2*)(p + 4);
        float2 a3 = *(const float2*)(p + 6);
        float2 a4 = *(const float2*)(p + 8);
        float x0 = a0.x, x1 = a0.y, x2 = a1.x, x3 = a1.y, x4 = a2.x;
        float x5 = a2.y, x6 = a3.x, x7 = a3.y, x8 = a4.x, x9 = a4.y;
        float m = fmaxf(x0, x1);
        m = fmaxf(m, x2); m = fmaxf(m, x3); m = fmaxf(m, x4);
        m = fmaxf(m, x5); m = fmaxf(m, x6); m = fmaxf(m, x7);
        m = fmaxf(m, x8); m = fmaxf(m, x9);
        float e0v = __expf((x0 - m) * 100.0f);
        float e1v = __expf((x1 - m) * 100.0f);
        float e2v = __expf((x2 - m) * 100.0f);
        float e3v = __expf((x3 - m) * 100.0f);
        float e4v = __expf((x4 - m) * 100.0f);
        float e5v = __expf((x5 - m) * 100.0f);
        float e6v = __expf((x6 - m) * 100.0f);
        float e7v = __expf((x7 - m) * 100.0f);
        float e8v = __expf((x8 - m) * 100.0f);
        float e9v = __expf((x9 - m) * 100.0f);
        float den = e0v + e1v + e2v + e3v + e4v + e5v + e6v + e7v + e8v + e9v;
        float num = e1v + e2v * 2.0f + e3v * 3.0f + e4v * 4.0f +
                    e5v * 5.0f + e6v * 6.0f + e7v * 7.0f + e8v * 8.0f + e9v * 9.0f;
        float contrib = num * __builtin_amdgcn_rcpf(den) * powv;   // den in [1,10]

        contrib += __shfl_xor(contrib, 1);
        contrib += __shfl_xor(contrib, 2);
        contrib += __shfl_xor(contrib, 4);
        if (dpos == 0)
            s_init[(c * 64 + lane) >> 3] = contrib;   // = el*9 + node
    }

    __syncthreads();    // single-wave: reduces to the needed waitcnt drain

    // ---- phase 2: DAG, one lane per element (8 lanes active) ----
    if (lane < EPB) {
        const int el = lane;
        float vmag16, sgn[NT], logm[NT], sv[NT];
        #pragma unroll
        for (int n = 0; n < NI; ++n) {
            float v = s_init[el * 9 + n];
            v = fminf(fmaxf(v, MAG_MIN), MAG_MAX);
            float sg = s_vs[el * NT + n];
            sgn[n] = sg; logm[n] = __logf(v); sv[n] = sg * v;
        }
        #pragma unroll
        for (int n = NI; n < NT; ++n) {
            sgn[n] = 0.0f; logm[n] = LOG_MAG_MIN; sv[n] = 0.0f;
        }
        vmag16 = 0.0f;

        float sgn16 = 0.0f;
        #pragma unroll
        for (int step = 0; step < DEPTH; ++step) {
            const int valid = NI + step;
            float g  = s_G[el * 9 + step];
            float og = 1.0f - g;
            float R = 0.0f;
            float prod = 1.0f;
            #pragma unroll
            for (int n = 0; n < NT; ++n) {
                if (n < valid) {
                    float o = s_O[el * 136 + step * 17 + n];
                    float mixed = logm[n] * og + sv[n] * g;
                    R += o * mixed;
                    float wgt = sgn[n] * fabsf(o) * 2.0f + 1.0f;
                    prod *= wgt;
                }
            }
            float linear_sign = tanh_fast(R * 10000.0f);
            float log_sign    = tanh_fast(prod * 10000.0f);
            float s_new = g * linear_sign + og * log_sign;
            float linear_mag  = fminf(fabsf(R), MAG_MAX);
            float Rc = fminf(fmaxf(R, -LOG_LIM), LOG_LIM);
            float log_mag_res = __expf(Rc);
            float m_new = g * linear_mag + og * log_mag_res;
            m_new = fminf(fmaxf(m_new, MAG_MIN), MAG_MAX);
            s_new = fminf(fmaxf(s_new, -1.0f), 1.0f);
            if (step < 7) {
                const int idx = NI + step;        // 9..15, compile-time
                sgn[idx]  = s_new;
                logm[idx] = __logf(m_new);
                sv[idx]   = s_new * m_new;
            } else {
                sgn16 = s_new; vmag16 = m_new;    // node 16: never re-read
            }
        }
        out[e0 + el] = sgn16 * vmag16;
    }
}

extern "C" void kernel_launch(void* const* d_in, const int* in_sizes, int n_in,
                              void* d_out, int out_size, void* d_ws, size_t ws_size,
                              hipStream_t stream) {
    const float* dl  = (const float*)d_in[0];   // digit_logits [B,T,9,8,10]
    const float* vsg = (const float*)d_in[1];   // V_sign       [B,T,17]
    const float* Og  = (const float*)d_in[2];   // O            [B,T,8,17]
    const float* Gg  = (const float*)d_in[3];   // G            [B,T,8]
    float* out = (float*)d_out;

    const int ne = out_size;                    // 32768
    const int blocks = ne / EPB;                // 4096
    dag_exec_kernel<<<blocks, THREADS, 0, stream>>>(dl, vsg, Og, Gg, out);
}

// Round 7
// 28.860 us; speedup vs baseline: 1.1670x; 1.1670x over previous
//
#include <hip/hip_runtime.h>
#include <math.h>

#define THREADS    256
#define EPB        32      // elements per block
#define NI         9
#define NT         17
#define DEPTH      8

#define MAG_MAX    1e28f
#define MAG_MIN    1e-12f
#define LOG_LIM    100.0f
#define LOG_MAG_MIN (-27.631021115928547f)

// LDS layout (dwords) inside one s_mem block, total 5440 dw = 21760 B:
//   [0,    4352)  s_O   [32][136]   (digit buffer s_dl aliases [0,2560))
//   [4352, 4896)  s_vs  [32][17]
//   [4896, 5152)  s_G   [32][8]
//   [5152, 5440)  s_init[32][9]
#define O_OFF     0
#define VS_OFF    4352
#define G_OFF     4896
#define INIT_OFF  5152
#define TOTAL_DW  5440

typedef __attribute__((address_space(1))) const unsigned char gconst_byte;
typedef __attribute__((address_space(3))) unsigned char lds_byte;

__device__ __forceinline__ void gl_lds16(const float* g, float* l) {
    __builtin_amdgcn_global_load_lds((gconst_byte*)(const void*)g,
                                     (lds_byte*)(void*)l, 16, 0, 0);
}

__device__ __forceinline__ float tanh_fast(float x) {
    float e = __expf(2.0f * x);
    return 1.0f - 2.0f / (e + 1.0f);
}

__global__ __launch_bounds__(THREADS, 7)
void dag_exec_kernel(const float* __restrict__ dl,   // [NE,9,8,10]
                     const float* __restrict__ vsg,  // [NE,17]
                     const float* __restrict__ Og,   // [NE,8,17]
                     const float* __restrict__ Gg,   // [NE,8]
                     float* __restrict__ out)        // [NE]
{
    __shared__ float s_mem[TOTAL_DW];

    const int tid  = threadIdx.x;
    const int lane = tid & 63;
    const int w    = tid >> 6;          // 4 waves
    const long e0  = (long)blockIdx.x * EPB;

    const float* Dg = dl + e0 * 720;
    const float* gw = Dg + w * 640;     // wave slice; chunk c at +c*2560
    float* lb = s_mem + w * 640;        // s_dl alias inside O region

    // ---- chunk 0 and 1 -> regs first (so their vmcnt wait excludes O gl_lds) ----
    float4 A0[3], A1[3];
    float2 A2[3];
    A0[0] = *(const float4*)(gw + lane * 4);
    A1[0] = *(const float4*)(gw + 256 + lane * 4);
    A2[0] = *(const float2*)(gw + 512 + lane * 2);
    A0[1] = *(const float4*)(gw + 2560 + lane * 4);
    A1[1] = *(const float4*)(gw + 2560 + 256 + lane * 4);
    A2[1] = *(const float2*)(gw + 2560 + 512 + lane * 2);

    const float* Ob = Og + e0 * 136;    // 4352 dw per block

    // ---- EARLY O: non-aliased region, dwords [2560, 4352) = 7 x 1KB segs ----
    {
        // seg i covers dw 2560+i*256; waves: w -> {w, w+4(if exists)}
        gl_lds16(Ob + 2560 + w * 256 + lane * 4, s_mem + 2560 + w * 256);
        if (w < 3)
            gl_lds16(Ob + 2560 + (w + 4) * 256 + lane * 4, s_mem + 2560 + (w + 4) * 256);
    }
    // ---- V_sign, G (small, coalesced) ----
    {
        const float* Vb = vsg + e0 * NT;
        s_mem[VS_OFF + tid]       = Vb[tid];
        s_mem[VS_OFF + tid + 256] = Vb[tid + 256];
        if (tid < 32) s_mem[VS_OFF + tid + 512] = Vb[tid + 512];
        s_mem[G_OFF + tid] = Gg[e0 * 8 + tid];          // [32][8] linear
    }

    const int dpos = tid & 7;
    const float powv = (dpos == 0) ? 1000.0f : (dpos == 1) ? 100.0f : (dpos == 2) ? 10.0f :
                       (dpos == 3) ? 1.0f    : (dpos == 4) ? 0.1f   : (dpos == 5) ? 0.01f :
                       (dpos == 6) ? 0.001f  : 0.0001f;

    // ---- phase 1: 9 chunks, rolling depth-2 pipeline, wave-local, no barriers ----
    #pragma unroll
    for (int c = 0; c < 9; ++c) {
        const int cur = c % 3;
        const int pre = (c + 2) % 3;
        if (c + 2 < 9) {
            const float* gn = gw + (c + 2) * 2560;
            A0[pre] = *(const float4*)(gn + lane * 4);
            A1[pre] = *(const float4*)(gn + 256 + lane * 4);
            A2[pre] = *(const float2*)(gn + 512 + lane * 2);
        }

        *(float4*)(lb + lane * 4)       = A0[cur];
        *(float4*)(lb + 256 + lane * 4) = A1[cur];
        *(float2*)(lb + 512 + lane * 2) = A2[cur];

        const float* p = lb + lane * 10;
        float2 a0 = *(const float2*)(p + 0);
        float2 a1 = *(const float2*)(p + 2);
        float2 a2 = *(const float2*)(p + 4);
        float2 a3 = *(const float2*)(p + 6);
        float2 a4 = *(const float2*)(p + 8);
        float x0 = a0.x, x1 = a0.y, x2 = a1.x, x3 = a1.y, x4 = a2.x;
        float x5 = a2.y, x6 = a3.x, x7 = a3.y, x8 = a4.x, x9 = a4.y;
        float m = fmaxf(fmaxf(fmaxf(fmaxf(x0, x1), fmaxf(x2, x3)),
                              fmaxf(fmaxf(x4, x5), fmaxf(x6, x7))),
                        fmaxf(x8, x9));
        float e0v = __expf((x0 - m) * 100.0f);
        float e1v = __expf((x1 - m) * 100.0f);
        float e2v = __expf((x2 - m) * 100.0f);
        float e3v = __expf((x3 - m) * 100.0f);
        float e4v = __expf((x4 - m) * 100.0f);
        float e5v = __expf((x5 - m) * 100.0f);
        float e6v = __expf((x6 - m) * 100.0f);
        float e7v = __expf((x7 - m) * 100.0f);
        float e8v = __expf((x8 - m) * 100.0f);
        float e9v = __expf((x9 - m) * 100.0f);
        float den = e0v + e1v + e2v + e3v + e4v + e5v + e6v + e7v + e8v + e9v;
        float num = e1v + e2v * 2.0f + e3v * 3.0f + e4v * 4.0f +
                    e5v * 5.0f + e6v * 6.0f + e7v * 7.0f + e8v * 8.0f + e9v * 9.0f;
        float contrib = num * __builtin_amdgcn_rcpf(den) * powv;  // den in [1,10]

        contrib += __shfl_xor(contrib, 1);
        contrib += __shfl_xor(contrib, 2);
        contrib += __shfl_xor(contrib, 4);
        if (dpos == 0)
            s_mem[INIT_OFF + ((c * 256 + tid) >> 3)] = contrib;
    }

    // ---- barrier #1: all waves done reading s_dl region ----
    __syncthreads();

    // ---- LATE O: aliased region, dwords [0, 2560) = 10 x 1KB segs ----
    {
        // waves: w=0:{0,4,8} w=1:{1,5,9} w=2:{2,6} w=3:{3,7}
        gl_lds16(Ob + w * 256 + lane * 4,       s_mem + w * 256);
        gl_lds16(Ob + (w + 4) * 256 + lane * 4, s_mem + (w + 4) * 256);
        if (w < 2)
            gl_lds16(Ob + (w + 8) * 256 + lane * 4, s_mem + (w + 8) * 256);
    }

    // ---- barrier #2: drains each wave's vmcnt -> all O in LDS ----
    __syncthreads();

    // ---- phase 2: DAG, one thread per element ----
    if (tid < EPB) {
        float sgn[NT], logm[NT], sv[NT];
        #pragma unroll
        for (int n = 0; n < NI; ++n) {
            float v = s_mem[INIT_OFF + tid * 9 + n];
            v = fminf(fmaxf(v, MAG_MIN), MAG_MAX);
            float sg = s_mem[VS_OFF + tid * NT + n];
            sgn[n] = sg; logm[n] = __logf(v); sv[n] = sg * v;
        }
        #pragma unroll
        for (int n = NI; n < NT; ++n) {
            sgn[n] = 0.0f; logm[n] = LOG_MAG_MIN; sv[n] = 0.0f;
        }

        float sgn16 = 0.0f, mag16 = 0.0f;
        #pragma unroll
        for (int step = 0; step < DEPTH; ++step) {
            const int valid = NI + step;
            float g  = s_mem[G_OFF + tid * 8 + step];
            float og = 1.0f - g;
            float R = 0.0f;
            float prod = 1.0f;
            #pragma unroll
            for (int n = 0; n < NT; ++n) {
                if (n < valid) {
                    float o = s_mem[O_OFF + tid * 136 + step * 17 + n];
                    float mixed = logm[n] * og + sv[n] * g;
                    R += o * mixed;
                    float wgt = sgn[n] * fabsf(o) * 2.0f + 1.0f;
                    prod *= wgt;
                }
            }
            float linear_sign = tanh_fast(R * 10000.0f);
            float log_sign    = tanh_fast(prod * 10000.0f);
            float s_new = g * linear_sign + og * log_sign;
            float linear_mag  = fminf(fabsf(R), MAG_MAX);
            float Rc = fminf(fmaxf(R, -LOG_LIM), LOG_LIM);
            float log_mag_res = __expf(Rc);
            float m_new = g * linear_mag + og * log_mag_res;
            m_new = fminf(fmaxf(m_new, MAG_MIN), MAG_MAX);
            s_new = fminf(fmaxf(s_new, -1.0f), 1.0f);
            if (step < 7) {
                const int idx = NI + step;     // compile-time under unroll
                sgn[idx]  = s_new;
                logm[idx] = __logf(m_new);
                sv[idx]   = s_new * m_new;
            } else {
                sgn16 = s_new; mag16 = m_new;  // node 16 never re-read
            }
        }
        out[e0 + tid] = sgn16 * mag16;
    }
}

extern "C" void kernel_launch(void* const* d_in, const int* in_sizes, int n_in,
                              void* d_out, int out_size, void* d_ws, size_t ws_size,
                              hipStream_t stream) {
    const float* dl  = (const float*)d_in[0];   // digit_logits [B,T,9,8,10]
    const float* vsg = (const float*)d_in[1];   // V_sign       [B,T,17]
    const float* Og  = (const float*)d_in[2];   // O            [B,T,8,17]
    const float* Gg  = (const float*)d_in[3];   // G            [B,T,8]
    float* out = (float*)d_out;

    const int ne = out_size;                    // 32768
    const int blocks = ne / EPB;                // 1024
    dag_exec_kernel<<<blocks, THREADS, 0, stream>>>(dl, vsg, Og, Gg, out);
}

// Round 8
// 27.209 us; speedup vs baseline: 1.2378x; 1.0607x over previous
//
#include <hip/hip_runtime.h>
#include <math.h>

#define THREADS    256
#define EPB        32      // elements per block
#define NI         9
#define NT         17
#define DEPTH      8

#define MAG_MAX    1e28f
#define MAG_MIN    1e-12f
#define LOG_LIM    100.0f
#define LOG_MAG_MIN (-27.631021115928547f)

// LDS layout (dwords), total 5440 dw = 21760 B -> 7 blocks/CU:
//   [0,    4352)  s_O   [32][136]   (digit buffer s_dl aliases [0,2560))
//   [4352, 4896)  s_vs  [32][17]
//   [4896, 5152)  s_G   [32][8]
//   [5152, 5440)  s_init[32][9]
#define O_OFF     0
#define VS_OFF    4352
#define G_OFF     4896
#define INIT_OFF  5152
#define TOTAL_DW  5440

typedef __attribute__((address_space(1))) const unsigned char gconst_byte;
typedef __attribute__((address_space(3))) unsigned char lds_byte;

__device__ __forceinline__ void gl_lds16(const float* g, float* l) {
    __builtin_amdgcn_global_load_lds((gconst_byte*)(const void*)g,
                                     (lds_byte*)(void*)l, 16, 0, 0);
}

__device__ __forceinline__ float tanh_fast(float x) {
    float e = __expf(2.0f * x);
    return 1.0f - 2.0f / (e + 1.0f);
}

__global__ __launch_bounds__(THREADS, 4)
void dag_exec_kernel(const float* __restrict__ dl,   // [NE,9,8,10]
                     const float* __restrict__ vsg,  // [NE,17]
                     const float* __restrict__ Og,   // [NE,8,17]
                     const float* __restrict__ Gg,   // [NE,8]
                     float* __restrict__ out)        // [NE]
{
    __shared__ float s_mem[TOTAL_DW];

    const int tid  = threadIdx.x;
    const int lane = tid & 63;
    const int w    = tid >> 6;          // 4 waves
    const long e0  = (long)blockIdx.x * EPB;

    const float* Dg = dl + e0 * 720;
    const float* gw = Dg + w * 640;     // wave slice; chunk c at +c*2560
    float* lb = s_mem + w * 640;        // digit buffer aliases O[0,2560)

    // ---- chunk 0 -> regs (coalesced) ----
    float4 r0 = *(const float4*)(gw + lane * 4);
    float4 r1 = *(const float4*)(gw + 256 + lane * 4);
    float2 r2 = *(const float2*)(gw + 512 + lane * 2);

    const float* Ob = Og + e0 * 136;    // 4352 dw per block

    // ---- EARLY O: non-aliased region, dwords [2560, 4352) = 7 x 1KB segs ----
    {
        gl_lds16(Ob + 2560 + w * 256 + lane * 4, s_mem + 2560 + w * 256);
        if (w < 3)
            gl_lds16(Ob + 2560 + (w + 4) * 256 + lane * 4, s_mem + 2560 + (w + 4) * 256);
    }
    // ---- V_sign, G (small, coalesced) ----
    {
        const float* Vb = vsg + e0 * NT;
        s_mem[VS_OFF + tid]       = Vb[tid];
        s_mem[VS_OFF + tid + 256] = Vb[tid + 256];
        if (tid < 32) s_mem[VS_OFF + tid + 512] = Vb[tid + 512];
        s_mem[G_OFF + tid] = Gg[e0 * 8 + tid];          // [32][8] linear
    }

    const int dpos = tid & 7;
    const float powv = (dpos == 0) ? 1000.0f : (dpos == 1) ? 100.0f : (dpos == 2) ? 10.0f :
                       (dpos == 3) ? 1.0f    : (dpos == 4) ? 0.1f   : (dpos == 5) ? 0.01f :
                       (dpos == 6) ? 0.001f  : 0.0001f;

    // ---- phase 1: 9 chunks, depth-1 prefetch, wave-local, no barriers ----
    #pragma unroll
    for (int c = 0; c < 9; ++c) {
        float4 n0, n1; float2 n2;
        if (c < 8) {                               // issue next-chunk loads
            const float* gn = gw + (c + 1) * 2560;
            n0 = *(const float4*)(gn + lane * 4);
            n1 = *(const float4*)(gn + 256 + lane * 4);
            n2 = *(const float2*)(gn + 512 + lane * 2);
        }
        __builtin_amdgcn_sched_barrier(0);         // pin loads above the ds_write

        // write chunk c (its loads were issued one iteration ago)
        *(float4*)(lb + lane * 4)       = r0;
        *(float4*)(lb + 256 + lane * 4) = r1;
        *(float2*)(lb + 512 + lane * 2) = r2;

        const float* p = lb + lane * 10;           // own slot, own wave region
        float2 a0 = *(const float2*)(p + 0);
        float2 a1 = *(const float2*)(p + 2);
        float2 a2 = *(const float2*)(p + 4);
        float2 a3 = *(const float2*)(p + 6);
        float2 a4 = *(const float2*)(p + 8);
        float x0 = a0.x, x1 = a0.y, x2 = a1.x, x3 = a1.y, x4 = a2.x;
        float x5 = a2.y, x6 = a3.x, x7 = a3.y, x8 = a4.x, x9 = a4.y;
        float m = fmaxf(fmaxf(fmaxf(fmaxf(x0, x1), fmaxf(x2, x3)),
                              fmaxf(fmaxf(x4, x5), fmaxf(x6, x7))),
                        fmaxf(x8, x9));
        float e0v = __expf((x0 - m) * 100.0f);
        float e1v = __expf((x1 - m) * 100.0f);
        float e2v = __expf((x2 - m) * 100.0f);
        float e3v = __expf((x3 - m) * 100.0f);
        float e4v = __expf((x4 - m) * 100.0f);
        float e5v = __expf((x5 - m) * 100.0f);
        float e6v = __expf((x6 - m) * 100.0f);
        float e7v = __expf((x7 - m) * 100.0f);
        float e8v = __expf((x8 - m) * 100.0f);
        float e9v = __expf((x9 - m) * 100.0f);
        float den = e0v + e1v + e2v + e3v + e4v + e5v + e6v + e7v + e8v + e9v;
        float num = e1v + e2v * 2.0f + e3v * 3.0f + e4v * 4.0f +
                    e5v * 5.0f + e6v * 6.0f + e7v * 7.0f + e8v * 8.0f + e9v * 9.0f;
        float contrib = num * __builtin_amdgcn_rcpf(den) * powv;  // den in [1,10]

        contrib += __shfl_xor(contrib, 1);
        contrib += __shfl_xor(contrib, 2);
        contrib += __shfl_xor(contrib, 4);
        if (dpos == 0)
            s_mem[INIT_OFF + ((c * 256 + tid) >> 3)] = contrib;

        if (c < 8) { r0 = n0; r1 = n1; r2 = n2; }
    }

    // ---- barrier #1: all waves done reading the aliased digit region ----
    __syncthreads();

    // ---- LATE O: aliased region, dwords [0, 2560) = 10 x 1KB segs ----
    {
        gl_lds16(Ob + w * 256 + lane * 4,       s_mem + w * 256);
        gl_lds16(Ob + (w + 4) * 256 + lane * 4, s_mem + (w + 4) * 256);
        if (w < 2)
            gl_lds16(Ob + (w + 8) * 256 + lane * 4, s_mem + (w + 8) * 256);
    }

    // ---- barrier #2: per-wave vmcnt drain + barrier -> all O visible ----
    __syncthreads();

    // ---- phase 2: DAG, one thread per element ----
    if (tid < EPB) {
        float sgn[NT], logm[NT], sv[NT];
        #pragma unroll
        for (int n = 0; n < NI; ++n) {
            float v = s_mem[INIT_OFF + tid * 9 + n];
            v = fminf(fmaxf(v, MAG_MIN), MAG_MAX);
            float sg = s_mem[VS_OFF + tid * NT + n];
            sgn[n] = sg; logm[n] = __logf(v); sv[n] = sg * v;
        }
        #pragma unroll
        for (int n = NI; n < NT; ++n) {
            sgn[n] = 0.0f; logm[n] = LOG_MAG_MIN; sv[n] = 0.0f;
        }

        float sgn16 = 0.0f, mag16 = 0.0f;
        #pragma unroll
        for (int step = 0; step < DEPTH; ++step) {
            const int valid = NI + step;
            float g  = s_mem[G_OFF + tid * 8 + step];
            float og = 1.0f - g;
            float R = 0.0f;
            float prod = 1.0f;
            #pragma unroll
            for (int n = 0; n < NT; ++n) {
                if (n < valid) {
                    float o = s_mem[O_OFF + tid * 136 + step * 17 + n];
                    float mixed = logm[n] * og + sv[n] * g;
                    R += o * mixed;
                    float wgt = sgn[n] * fabsf(o) * 2.0f + 1.0f;
                    prod *= wgt;
                }
            }
            float linear_sign = tanh_fast(R * 10000.0f);
            float log_sign    = tanh_fast(prod * 10000.0f);
            float s_new = g * linear_sign + og * log_sign;
            float linear_mag  = fminf(fabsf(R), MAG_MAX);
            float Rc = fminf(fmaxf(R, -LOG_LIM), LOG_LIM);
            float log_mag_res = __expf(Rc);
            float m_new = g * linear_mag + og * log_mag_res;
            m_new = fminf(fmaxf(m_new, MAG_MIN), MAG_MAX);
            s_new = fminf(fmaxf(s_new, -1.0f), 1.0f);
            if (step < 7) {
                const int idx = NI + step;     // compile-time under unroll
                sgn[idx]  = s_new;
                logm[idx] = __logf(m_new);
                sv[idx]   = s_new * m_new;
            } else {
                sgn16 = s_new; mag16 = m_new;  // node 16 never re-read
            }
        }
        out[e0 + tid] = sgn16 * mag16;
    }
}

extern "C" void kernel_launch(void* const* d_in, const int* in_sizes, int n_in,
                              void* d_out, int out_size, void* d_ws, size_t ws_size,
                              hipStream_t stream) {
    const float* dl  = (const float*)d_in[0];   // digit_logits [B,T,9,8,10]
    const float* vsg = (const float*)d_in[1];   // V_sign       [B,T,17]
    const float* Og  = (const float*)d_in[2];   // O            [B,T,8,17]
    const float* Gg  = (const float*)d_in[3];   // G            [B,T,8]
    float* out = (float*)d_out;

    const int ne = out_size;                    // 32768
    const int blocks = ne / EPB;                // 1024
    dag_exec_kernel<<<blocks, THREADS, 0, stream>>>(dl, vsg, Og, Gg, out);
}